// Round 1
// baseline (1330.974 us; speedup 1.0000x reference)
//
#include <hip/hip_runtime.h>
#include <hip/hip_bf16.h>
#include <cstdint>

#define DF(p) ((const float*)(p))
#define DI(p) ((const int*)(p))

static __device__ __forceinline__ float elu_f(float v){
  return v > 0.0f ? v : expm1f(v);
}

// ---------------- CSR build ----------------

__global__ void hist_kernel(const int* __restrict__ dst, int* __restrict__ cnt, int E){
  int e = blockIdx.x*blockDim.x + threadIdx.x;
  if (e < E) atomicAdd(&cnt[dst[e]], 1);
}

// in-place exclusive scan within 256-blocks; bsum gets block inclusive totals
__global__ void scan1_kernel(int* __restrict__ data, int* __restrict__ bsum, int total){
  __shared__ int s[256];
  int i = blockIdx.x*256 + threadIdx.x;
  int v = (i < total) ? data[i] : 0;
  s[threadIdx.x] = v;
  __syncthreads();
  for (int off=1; off<256; off<<=1){
    int t = (threadIdx.x >= (unsigned)off) ? s[threadIdx.x - off] : 0;
    __syncthreads();
    s[threadIdx.x] += t;
    __syncthreads();
  }
  if (i < total) data[i] = s[threadIdx.x] - v;   // exclusive within block
  if (threadIdx.x == 255) bsum[blockIdx.x] = s[255];
}

// single block exclusive scan of nb block sums (nb <= 1024)
__global__ void scan2_kernel(int* __restrict__ bsum, int nb){
  __shared__ int s[1024];
  int t = threadIdx.x;
  int v = (t < nb) ? bsum[t] : 0;
  s[t] = v;
  __syncthreads();
  for (int off=1; off<1024; off<<=1){
    int x = (t >= off) ? s[t - off] : 0;
    __syncthreads();
    s[t] += x;
    __syncthreads();
  }
  if (t < nb) bsum[t] = s[t] - v;   // exclusive
}

__global__ void scan3_kernel(int* __restrict__ rowptr, const int* __restrict__ bsum,
                             int* __restrict__ row_off, int total, int N){
  int i = blockIdx.x*256 + threadIdx.x;
  if (i < total){
    int v = rowptr[i] + bsum[blockIdx.x];
    rowptr[i] = v;
    if (i < N) row_off[i] = v;
  }
}

__global__ void fill_kernel(const int* __restrict__ src, const int* __restrict__ dst,
                            const float* __restrict__ ew, int* __restrict__ row_off,
                            int* __restrict__ csr_src, float4* __restrict__ csr_w, int E){
  int e = blockIdx.x*blockDim.x + threadIdx.x;
  if (e >= E) return;
  int d = dst[e];
  int pos = atomicAdd(&row_off[d], 1);
  csr_src[pos] = src[e];
  float4 w;
  w.x = ew[e];
  w.y = ew[(size_t)E + e];
  w.z = ew[2*(size_t)E + e];
  w.w = ew[3*(size_t)E + e];
  csr_w[pos] = w;
}

// ---------------- dense: y[n][j] (float4 over channels) = sum_i x[n][i] * W[r][i][j] ----------------

// layer 1 with fused concat(one_hot[20], features[44])
__global__ __launch_bounds__(256) void dense1_kernel(
    const float* __restrict__ one_hot, const float* __restrict__ features,
    const float* __restrict__ W, float4* __restrict__ y, int N){
  constexpr int DIN = 64, DOUT = 20;
  int n = blockIdx.x*blockDim.x + threadIdx.x;
  if (n >= N) return;
  float4 acc[DOUT];
  #pragma unroll
  for (int j=0;j<DOUT;j++) acc[j] = make_float4(0.f,0.f,0.f,0.f);

  #pragma unroll 4
  for (int i=0;i<20;i++){
    float xi = one_hot[(size_t)n*20 + i];
    #pragma unroll
    for (int j=0;j<DOUT;j++){
      acc[j].x += xi * W[0*DIN*DOUT + i*DOUT + j];
      acc[j].y += xi * W[1*DIN*DOUT + i*DOUT + j];
      acc[j].z += xi * W[2*DIN*DOUT + i*DOUT + j];
      acc[j].w += xi * W[3*DIN*DOUT + i*DOUT + j];
    }
  }
  #pragma unroll 4
  for (int i=20;i<64;i++){
    float xi = features[(size_t)n*44 + (i-20)];
    #pragma unroll
    for (int j=0;j<DOUT;j++){
      acc[j].x += xi * W[0*DIN*DOUT + i*DOUT + j];
      acc[j].y += xi * W[1*DIN*DOUT + i*DOUT + j];
      acc[j].z += xi * W[2*DIN*DOUT + i*DOUT + j];
      acc[j].w += xi * W[3*DIN*DOUT + i*DOUT + j];
    }
  }
  #pragma unroll
  for (int j=0;j<DOUT;j++) y[(size_t)n*DOUT + j] = acc[j];
}

template<int DIN, int DOUT>
__global__ __launch_bounds__(256) void dense_kernel(
    const float* __restrict__ x, const float* __restrict__ W,
    float4* __restrict__ y, int N){
  int n = blockIdx.x*blockDim.x + threadIdx.x;
  if (n >= N) return;
  float4 acc[DOUT];
  #pragma unroll
  for (int j=0;j<DOUT;j++) acc[j] = make_float4(0.f,0.f,0.f,0.f);
  #pragma unroll 4
  for (int i=0;i<DIN;i++){
    float xi = x[(size_t)n*DIN + i];
    #pragma unroll
    for (int j=0;j<DOUT;j++){
      acc[j].x += xi * W[0*DIN*DOUT + i*DOUT + j];
      acc[j].y += xi * W[1*DIN*DOUT + i*DOUT + j];
      acc[j].z += xi * W[2*DIN*DOUT + i*DOUT + j];
      acc[j].w += xi * W[3*DIN*DOUT + i*DOUT + j];
    }
  }
  #pragma unroll
  for (int j=0;j<DOUT;j++) y[(size_t)n*DOUT + j] = acc[j];
}

// ---------------- aggregation: xout[d][j] = elu( b[j] + sum_{k in row(d)} dot(w4[k], y[src[k]][j]) ) ----------------

template<int DOUT>
__global__ __launch_bounds__(256) void agg_kernel(
    const int* __restrict__ rowptr, const int* __restrict__ csr_src,
    const float4* __restrict__ csr_w, const float4* __restrict__ y,
    const float* __restrict__ b, float* __restrict__ xout, int N){
  constexpr int JPL = DOUT/4;     // output dims per lane (4-lane team per node)
  int team = threadIdx.x >> 2;
  int lane = threadIdx.x & 3;
  int node = blockIdx.x*64 + team;
  if (node >= N) return;
  int beg = rowptr[node];
  int end = rowptr[node+1];
  float acc[JPL];
  #pragma unroll
  for (int jj=0;jj<JPL;jj++) acc[jj] = 0.f;
  for (int k=beg; k<end; ++k){
    int s = csr_src[k];
    float4 w = csr_w[k];
    const float4* yr = y + (size_t)s*DOUT;
    #pragma unroll
    for (int jj=0;jj<JPL;jj++){
      float4 v = yr[jj*4 + lane];
      acc[jj] += w.x*v.x + w.y*v.y + w.z*v.z + w.w*v.w;
    }
  }
  #pragma unroll
  for (int jj=0;jj<JPL;jj++){
    int j = jj*4 + lane;
    xout[(size_t)node*DOUT + j] = elu_f(acc[jj] + b[j]);
  }
}

// ---------------- final MLP: 4 -> 8 -> 4 -> 1 (elu, elu, sigmoid) ----------------

__global__ __launch_bounds__(256) void mlp_kernel(
    const float* __restrict__ x,
    const float* __restrict__ lw1, const float* __restrict__ lb1,
    const float* __restrict__ lw2, const float* __restrict__ lb2,
    const float* __restrict__ lw3, const float* __restrict__ lb3,
    float* __restrict__ out, int N){
  int n = blockIdx.x*blockDim.x + threadIdx.x;
  if (n >= N) return;
  float4 xv = ((const float4*)x)[n];
  float x0[4] = {xv.x, xv.y, xv.z, xv.w};
  float h1[8];
  #pragma unroll
  for (int j=0;j<8;j++){
    float a = lb1[j];
    #pragma unroll
    for (int i=0;i<4;i++) a += x0[i]*lw1[i*8+j];
    h1[j] = elu_f(a);
  }
  float h2[4];
  #pragma unroll
  for (int j=0;j<4;j++){
    float a = lb2[j];
    #pragma unroll
    for (int i=0;i<8;i++) a += h1[i]*lw2[i*4+j];
    h2[j] = elu_f(a);
  }
  float a = lb3[0];
  #pragma unroll
  for (int i=0;i<4;i++) a += h2[i]*lw3[i];
  out[n] = 1.0f / (1.0f + expf(-a));
}

// ---------------- launch ----------------

extern "C" void kernel_launch(void* const* d_in, const int* in_sizes, int n_in,
                              void* d_out, int out_size, void* d_ws, size_t ws_size,
                              hipStream_t stream){
  const float* one_hot  = DF(d_in[0]);
  const float* features = DF(d_in[1]);
  const int*   src      = DI(d_in[3]);
  const int*   dst      = DI(d_in[4]);
  const float* ew       = DF(d_in[5]);
  const float* W1 = DF(d_in[6]);  const float* b1 = DF(d_in[7]);
  const float* W2 = DF(d_in[8]);  const float* b2 = DF(d_in[9]);
  const float* W3 = DF(d_in[10]); const float* b3 = DF(d_in[11]);
  const float* W4 = DF(d_in[12]); const float* b4 = DF(d_in[13]);
  const float* W5 = DF(d_in[14]); const float* b5 = DF(d_in[15]);
  const float* lw1 = DF(d_in[16]); const float* lb1 = DF(d_in[17]);
  const float* lw2 = DF(d_in[18]); const float* lb2 = DF(d_in[19]);
  const float* lw3 = DF(d_in[20]); const float* lb3 = DF(d_in[21]);
  float* out = (float*)d_out;

  const int N = in_sizes[0] / 20;   // 100000
  const int E = in_sizes[3];        // 3200000

  auto align = [](size_t x){ return (x + 255) & ~((size_t)255); };
  char* ws = (char*)d_ws;
  size_t off = 0;
  int*    rowptr  = (int*)(ws + off);    off = align(off + (size_t)(N+1)*4);
  int*    row_off = (int*)(ws + off);    off = align(off + (size_t)N*4);
  int*    bsum    = (int*)(ws + off);    off = align(off + 4096);
  int*    csr_src = (int*)(ws + off);    off = align(off + (size_t)E*4);
  float4* csr_w   = (float4*)(ws + off); off = align(off + (size_t)E*16);
  float4* y       = (float4*)(ws + off); off = align(off + (size_t)N*80*4);
  float*  xA      = (float*)(ws + off);  off = align(off + (size_t)N*20*4);
  float*  xB      = (float*)(ws + off);  off = align(off + (size_t)N*20*4);
  (void)ws_size;

  const int TB = 256;
  const int nbE = (E + TB - 1) / TB;
  const int nbN = (N + TB - 1) / TB;
  const int nbA = (N + 63) / 64;       // 64 nodes (4-lane teams) per 256-thread block
  const int total = N + 1;
  const int nb1 = (total + 255) / 256;

  hipMemsetAsync(rowptr, 0, (size_t)(N+1)*4, stream);
  hist_kernel<<<nbE, TB, 0, stream>>>(dst, rowptr, E);
  scan1_kernel<<<nb1, 256, 0, stream>>>(rowptr, bsum, total);
  scan2_kernel<<<1, 1024, 0, stream>>>(bsum, nb1);
  scan3_kernel<<<nb1, 256, 0, stream>>>(rowptr, bsum, row_off, total, N);
  fill_kernel<<<nbE, TB, 0, stream>>>(src, dst, ew, row_off, csr_src, csr_w, E);

  dense1_kernel<<<nbN, TB, 0, stream>>>(one_hot, features, W1, y, N);
  agg_kernel<20><<<nbA, TB, 0, stream>>>(rowptr, csr_src, csr_w, y, b1, xA, N);

  dense_kernel<20,16><<<nbN, TB, 0, stream>>>(xA, W2, y, N);
  agg_kernel<16><<<nbA, TB, 0, stream>>>(rowptr, csr_src, csr_w, y, b2, xB, N);

  dense_kernel<16,12><<<nbN, TB, 0, stream>>>(xB, W3, y, N);
  agg_kernel<12><<<nbA, TB, 0, stream>>>(rowptr, csr_src, csr_w, y, b3, xA, N);

  dense_kernel<12,8><<<nbN, TB, 0, stream>>>(xA, W4, y, N);
  agg_kernel<8><<<nbA, TB, 0, stream>>>(rowptr, csr_src, csr_w, y, b4, xB, N);

  dense_kernel<8,4><<<nbN, TB, 0, stream>>>(xB, W5, y, N);
  agg_kernel<4><<<nbA, TB, 0, stream>>>(rowptr, csr_src, csr_w, y, b5, xA, N);

  mlp_kernel<<<nbN, TB, 0, stream>>>(xA, lw1, lb1, lw2, lb2, lw3, lb3, out, N);
}

// Round 2
// 1150.645 us; speedup vs baseline: 1.1567x; 1.1567x over previous
//
#include <hip/hip_runtime.h>
#include <hip/hip_bf16.h>
#include <cstdint>

#define DF(p) ((const float*)(p))
#define DI(p) ((const int*)(p))

static __device__ __forceinline__ float elu_f(float v){
  return v > 0.0f ? v : expm1f(v);
}

// ---------------- CSR build (unchanged from round 1) ----------------

__global__ void hist_kernel(const int* __restrict__ dst, int* __restrict__ cnt, int E){
  int e = blockIdx.x*blockDim.x + threadIdx.x;
  if (e < E) atomicAdd(&cnt[dst[e]], 1);
}

__global__ void scan1_kernel(int* __restrict__ data, int* __restrict__ bsum, int total){
  __shared__ int s[256];
  int i = blockIdx.x*256 + threadIdx.x;
  int v = (i < total) ? data[i] : 0;
  s[threadIdx.x] = v;
  __syncthreads();
  for (int off=1; off<256; off<<=1){
    int t = (threadIdx.x >= (unsigned)off) ? s[threadIdx.x - off] : 0;
    __syncthreads();
    s[threadIdx.x] += t;
    __syncthreads();
  }
  if (i < total) data[i] = s[threadIdx.x] - v;   // exclusive within block
  if (threadIdx.x == 255) bsum[blockIdx.x] = s[255];
}

__global__ void scan2_kernel(int* __restrict__ bsum, int nb){
  __shared__ int s[1024];
  int t = threadIdx.x;
  int v = (t < nb) ? bsum[t] : 0;
  s[t] = v;
  __syncthreads();
  for (int off=1; off<1024; off<<=1){
    int x = (t >= off) ? s[t - off] : 0;
    __syncthreads();
    s[t] += x;
    __syncthreads();
  }
  if (t < nb) bsum[t] = s[t] - v;   // exclusive
}

__global__ void scan3_kernel(int* __restrict__ rowptr, const int* __restrict__ bsum,
                             int* __restrict__ row_off, int total, int N){
  int i = blockIdx.x*256 + threadIdx.x;
  if (i < total){
    int v = rowptr[i] + bsum[blockIdx.x];
    rowptr[i] = v;
    if (i < N) row_off[i] = v;
  }
}

__global__ void fill_kernel(const int* __restrict__ src, const int* __restrict__ dst,
                            const float* __restrict__ ew, int* __restrict__ row_off,
                            int* __restrict__ csr_src, float4* __restrict__ csr_w, int E){
  int e = blockIdx.x*blockDim.x + threadIdx.x;
  if (e >= E) return;
  int d = dst[e];
  int pos = atomicAdd(&row_off[d], 1);
  csr_src[pos] = src[e];
  float4 w;
  w.x = ew[e];
  w.y = ew[(size_t)E + e];
  w.z = ew[2*(size_t)E + e];
  w.w = ew[3*(size_t)E + e];
  csr_w[pos] = w;
}

// ---------------- concat: xcat[n][0:64] = [one_hot(20), features(44)] ----------------

__global__ __launch_bounds__(256) void concat_kernel(
    const float* __restrict__ oh, const float* __restrict__ f,
    float* __restrict__ xcat, int N){
  int i = blockIdx.x*256 + threadIdx.x;
  if (i >= N*64) return;
  int n = i >> 6, j = i & 63;
  xcat[i] = (j < 20) ? oh[n*20 + j] : f[n*44 + (j-20)];
}

// ---------------- fused layer: pre-W aggregation + dense + bias + ELU ----------------
// z[n][r][i] = sum_{k in row(n)} w_r[k] * x[src[k]][i]    (i < XPI, pads are zero)
// xout[n][j] = elu( b[j] + sum_r sum_{i<DIN} z[n][r][i] * W[r][i][j] ),  pads j>=DOUT zeroed
// team of 16 lanes per node: lane = (r = lane>>2, q = lane&3); lane owns quarter q of
// channel r's accumulator (CH = XPI/4 floats).

template<int DIN, int DOUT, int XPI, int XPO>
__global__ __launch_bounds__(256) void layer_kernel(
    const int* __restrict__ rowptr, const int* __restrict__ csr_src,
    const float4* __restrict__ csr_w, const float* __restrict__ x,
    const float* __restrict__ W, const float* __restrict__ b,
    float* __restrict__ xout, int N)
{
  constexpr int CH  = XPI/4;   // floats per lane
  constexpr int CH4 = CH/4;    // float4s per lane
  __shared__ float Wl[4*DIN*DOUT];
  __shared__ float zs[16][4*XPI];

  for (int t = threadIdx.x; t < 4*DIN*DOUT; t += 256) Wl[t] = W[t];

  const int team = threadIdx.x >> 4;
  const int lane = threadIdx.x & 15;
  const int r    = lane >> 2;
  const int q    = lane & 3;
  const int node = blockIdx.x*16 + team;

  float acc[CH];
  #pragma unroll
  for (int i=0;i<CH;i++) acc[i] = 0.f;

  if (node < N){
    const int beg = rowptr[node];
    const int end = rowptr[node+1];
    for (int k = beg; k < end; ++k){
      const float w = ((const float*)(csr_w + k))[r];   // broadcast within r-group
      const int   s = csr_src[k];                        // broadcast within team
      const float4* xr = (const float4*)(x + (size_t)s*XPI + q*CH);
      #pragma unroll
      for (int t=0;t<CH4;t++){
        float4 v = xr[t];
        acc[4*t+0] += w*v.x;
        acc[4*t+1] += w*v.y;
        acc[4*t+2] += w*v.z;
        acc[4*t+3] += w*v.w;
      }
    }
    #pragma unroll
    for (int i=0;i<CH;i++) zs[team][r*XPI + q*CH + i] = acc[i];
  }
  __syncthreads();
  if (node < N){
    #pragma unroll
    for (int j = lane; j < XPO; j += 16){
      float v = 0.f;
      if (j < DOUT){
        float a = b[j];
        #pragma unroll
        for (int r2=0;r2<4;r2++){
          const float* zr = &zs[team][r2*XPI];
          const float* wr = &Wl[r2*DIN*DOUT + j];
          #pragma unroll 4
          for (int i=0;i<DIN;i++) a += zr[i]*wr[(size_t)i*DOUT];
        }
        v = elu_f(a);
      }
      xout[(size_t)node*XPO + j] = v;
    }
  }
}

// ---------------- final MLP: 4 -> 8 -> 4 -> 1 (elu, elu, sigmoid) ----------------

__global__ __launch_bounds__(256) void mlp_kernel(
    const float* __restrict__ x,
    const float* __restrict__ lw1, const float* __restrict__ lb1,
    const float* __restrict__ lw2, const float* __restrict__ lb2,
    const float* __restrict__ lw3, const float* __restrict__ lb3,
    float* __restrict__ out, int N){
  int n = blockIdx.x*blockDim.x + threadIdx.x;
  if (n >= N) return;
  float4 xv = ((const float4*)x)[n];
  float x0[4] = {xv.x, xv.y, xv.z, xv.w};
  float h1[8];
  #pragma unroll
  for (int j=0;j<8;j++){
    float a = lb1[j];
    #pragma unroll
    for (int i=0;i<4;i++) a += x0[i]*lw1[i*8+j];
    h1[j] = elu_f(a);
  }
  float h2[4];
  #pragma unroll
  for (int j=0;j<4;j++){
    float a = lb2[j];
    #pragma unroll
    for (int i=0;i<8;i++) a += h1[i]*lw2[i*4+j];
    h2[j] = elu_f(a);
  }
  float a = lb3[0];
  #pragma unroll
  for (int i=0;i<4;i++) a += h2[i]*lw3[i];
  out[n] = 1.0f / (1.0f + expf(-a));
}

// ---------------- launch ----------------

extern "C" void kernel_launch(void* const* d_in, const int* in_sizes, int n_in,
                              void* d_out, int out_size, void* d_ws, size_t ws_size,
                              hipStream_t stream){
  const float* one_hot  = DF(d_in[0]);
  const float* features = DF(d_in[1]);
  const int*   src      = DI(d_in[3]);
  const int*   dst      = DI(d_in[4]);
  const float* ew       = DF(d_in[5]);
  const float* W1 = DF(d_in[6]);  const float* b1 = DF(d_in[7]);
  const float* W2 = DF(d_in[8]);  const float* b2 = DF(d_in[9]);
  const float* W3 = DF(d_in[10]); const float* b3 = DF(d_in[11]);
  const float* W4 = DF(d_in[12]); const float* b4 = DF(d_in[13]);
  const float* W5 = DF(d_in[14]); const float* b5 = DF(d_in[15]);
  const float* lw1 = DF(d_in[16]); const float* lb1 = DF(d_in[17]);
  const float* lw2 = DF(d_in[18]); const float* lb2 = DF(d_in[19]);
  const float* lw3 = DF(d_in[20]); const float* lb3 = DF(d_in[21]);
  float* out = (float*)d_out;

  const int N = in_sizes[0] / 20;   // 100000
  const int E = in_sizes[3];        // 3200000

  auto align = [](size_t x){ return (x + 255) & ~((size_t)255); };
  char* ws = (char*)d_ws;
  size_t off = 0;
  int*    rowptr  = (int*)(ws + off);    off = align(off + (size_t)(N+1)*4);
  int*    row_off = (int*)(ws + off);    off = align(off + (size_t)N*4);
  int*    bsum    = (int*)(ws + off);    off = align(off + 4096);
  int*    csr_src = (int*)(ws + off);    off = align(off + (size_t)E*4);
  float4* csr_w   = (float4*)(ws + off); off = align(off + (size_t)E*16);
  float*  xcat    = (float*)(ws + off);  off = align(off + (size_t)N*64*4); // [N][64]
  float*  xA      = (float*)(ws + off);  off = align(off + (size_t)N*32*4); // [N][32] L1 out
  float*  xB      = (float*)(ws + off);  off = align(off + (size_t)N*16*4); // [N][16] L2/L5 out
  float*  xC      = (float*)(ws + off);  off = align(off + (size_t)N*16*4); // [N][16] L3 out
  (void)ws_size;

  const int TB = 256;
  const int nbE = (E + TB - 1) / TB;
  const int nbN = (N + TB - 1) / TB;
  const int nbL = (N + 15) / 16;        // 16 nodes (16-lane teams) per 256-thread block
  const int nbC = (N*64 + TB - 1) / TB;
  const int total = N + 1;
  const int nb1 = (total + 255) / 256;

  hipMemsetAsync(rowptr, 0, (size_t)(N+1)*4, stream);
  hist_kernel<<<nbE, TB, 0, stream>>>(dst, rowptr, E);
  scan1_kernel<<<nb1, 256, 0, stream>>>(rowptr, bsum, total);
  scan2_kernel<<<1, 1024, 0, stream>>>(bsum, nb1);
  scan3_kernel<<<nb1, 256, 0, stream>>>(rowptr, bsum, row_off, total, N);
  fill_kernel<<<nbE, TB, 0, stream>>>(src, dst, ew, row_off, csr_src, csr_w, E);

  concat_kernel<<<nbC, TB, 0, stream>>>(one_hot, features, xcat, N);

  // L1: 64 -> 20, in-rows 64 (exact), out-rows padded to 32
  layer_kernel<64,20,64,32><<<nbL, TB, 0, stream>>>(rowptr, csr_src, csr_w, xcat, W1, b1, xA, N);
  // L2: 20 -> 16, in 32 (12 zero pads), out 16
  layer_kernel<20,16,32,16><<<nbL, TB, 0, stream>>>(rowptr, csr_src, csr_w, xA, W2, b2, xB, N);
  // L3: 16 -> 12, in 16 (exact), out 16 (4 zero pads)
  layer_kernel<16,12,16,16><<<nbL, TB, 0, stream>>>(rowptr, csr_src, csr_w, xB, W3, b3, xC, N);
  // L4: 12 -> 8, in 16 (4 zero pads), out 16 (8 zero pads)
  layer_kernel<12, 8,16,16><<<nbL, TB, 0, stream>>>(rowptr, csr_src, csr_w, xC, W4, b4, xA, N);
  // L5: 8 -> 4, in 16 (8 zero pads), out 4 compact
  layer_kernel< 8, 4,16, 4><<<nbL, TB, 0, stream>>>(rowptr, csr_src, csr_w, xA, W5, b5, xB, N);

  mlp_kernel<<<nbN, TB, 0, stream>>>(xB, lw1, lb1, lw2, lb2, lw3, lb3, out, N);
}

// Round 3
// 996.440 us; speedup vs baseline: 1.3357x; 1.1548x over previous
//
#include <hip/hip_runtime.h>
#include <hip/hip_bf16.h>
#include <cstdint>

#define DF(p) ((const float*)(p))
#define DI(p) ((const int*)(p))

static __device__ __forceinline__ float elu_f(float v){
  return v > 0.0f ? v : expm1f(v);
}

// ---------------- CSR build ----------------

__global__ void hist_kernel(const int* __restrict__ dst, int* __restrict__ cnt,
                            int* __restrict__ rank, int E){
  int e = blockIdx.x*blockDim.x + threadIdx.x;
  if (e < E) rank[e] = atomicAdd(&cnt[dst[e]], 1);
}

__global__ void scan1_kernel(int* __restrict__ data, int* __restrict__ bsum, int total){
  __shared__ int s[256];
  int i = blockIdx.x*256 + threadIdx.x;
  int v = (i < total) ? data[i] : 0;
  s[threadIdx.x] = v;
  __syncthreads();
  for (int off=1; off<256; off<<=1){
    int t = (threadIdx.x >= (unsigned)off) ? s[threadIdx.x - off] : 0;
    __syncthreads();
    s[threadIdx.x] += t;
    __syncthreads();
  }
  if (i < total) data[i] = s[threadIdx.x] - v;   // exclusive within block
  if (threadIdx.x == 255) bsum[blockIdx.x] = s[255];
}

__global__ void scan2_kernel(int* __restrict__ bsum, int nb){
  __shared__ int s[1024];
  int t = threadIdx.x;
  int v = (t < nb) ? bsum[t] : 0;
  s[t] = v;
  __syncthreads();
  for (int off=1; off<1024; off<<=1){
    int x = (t >= off) ? s[t - off] : 0;
    __syncthreads();
    s[t] += x;
    __syncthreads();
  }
  if (t < nb) bsum[t] = s[t] - v;   // exclusive
}

__global__ void scan3_kernel(int* __restrict__ rowptr, const int* __restrict__ bsum, int total){
  int i = blockIdx.x*256 + threadIdx.x;
  if (i < total) rowptr[i] += bsum[blockIdx.x];
}

// atomic-free scatter: pos = rowptr[dst] + rank; 8B payload
__global__ void scatter_kernel(const int* __restrict__ src, const int* __restrict__ dst,
                               const int* __restrict__ rank, const int* __restrict__ rowptr,
                               int2* __restrict__ csr_se, int E){
  int e = blockIdx.x*blockDim.x + threadIdx.x;
  if (e >= E) return;
  int pos = rowptr[dst[e]] + rank[e];
  csr_se[pos] = make_int2(src[e], e);
}

// coalesced pass: expand (src,eid) -> csr_src + csr_w
__global__ void build_kernel(const int2* __restrict__ csr_se, const float* __restrict__ ew,
                             int* __restrict__ csr_src, float4* __restrict__ csr_w, int E){
  int p = blockIdx.x*blockDim.x + threadIdx.x;
  if (p >= E) return;
  int2 se = csr_se[p];
  csr_src[p] = se.x;
  size_t e = (size_t)se.y;
  csr_w[p] = make_float4(ew[e], ew[(size_t)E + e], ew[2*(size_t)E + e], ew[3*(size_t)E + e]);
}

// ---------------- concat: xcat[n][0:64] = [one_hot(20), features(44)] ----------------

__global__ __launch_bounds__(256) void concat_kernel(
    const float* __restrict__ oh, const float* __restrict__ f,
    float* __restrict__ xcat, int N){
  int i = blockIdx.x*256 + threadIdx.x;
  if (i >= N*64) return;
  int n = i >> 6, j = i & 63;
  xcat[i] = (j < 20) ? oh[n*20 + j] : f[n*44 + (j-20)];
}

// ---------------- fused layer: pre-W aggregation + dense + bias + ELU ----------------
// Phase 1: team of TS=XPI lanes per node, lane = element i. Per edge: one coalesced
//          row load (1 float/lane) + 4 FMA/lane (channels). Unrolled x4.
// Phase 2: thread (n = tid%NPB, j = tid/NPB): out[n][j] = elu(b[j] + sum_t zs[n][t]*Wt[j][t]),
//          t = r*XPI+i over R4 = 4*XPI terms, b128 reads, same-j lanes broadcast Wt.

template<int DIN, int DOUT, int XPI, int XPO>
__global__ __launch_bounds__(256) void layer_kernel(
    const int* __restrict__ rowptr, const int* __restrict__ csr_src,
    const float4* __restrict__ csr_w, const float* __restrict__ x,
    const float* __restrict__ W, const float* __restrict__ b,
    float* __restrict__ xout, int N)
{
  constexpr int TS  = XPI;
  constexpr int NPB = 256 / TS;
  constexpr int R4  = 4 * XPI;
  constexpr int ZS  = R4 + 4;   // padded node stride (floats)
  constexpr int WTS = R4 + 4;   // padded Wt row stride
  __shared__ float zs[NPB * ZS];
  __shared__ float Wt[DOUT * WTS];

  const int tid = threadIdx.x;

  // stage Wt[j][t] = (i<DIN) ? W[r][i][j] : 0   (t = r*XPI + i)
  for (int f = tid; f < DOUT * R4; f += 256){
    int jj = f / R4;
    int t  = f & (R4 - 1);
    int r  = t / XPI;
    int i  = t & (XPI - 1);
    Wt[jj * WTS + t] = (i < DIN) ? W[(r * DIN + i) * DOUT + jj] : 0.f;
  }

  // ---- phase 1 ----
  const int team = tid / TS;
  const int lane = tid & (TS - 1);
  const int node = blockIdx.x * NPB + team;
  if (node < N){
    const int beg = rowptr[node];
    const int end = rowptr[node + 1];
    float a0 = 0.f, a1 = 0.f, a2 = 0.f, a3 = 0.f;
    int k = beg;
    for (; k + 4 <= end; k += 4){
      int s0 = csr_src[k+0], s1 = csr_src[k+1], s2 = csr_src[k+2], s3 = csr_src[k+3];
      float4 w0 = csr_w[k+0], w1 = csr_w[k+1], w2 = csr_w[k+2], w3 = csr_w[k+3];
      float v0 = x[s0 * XPI + lane];
      float v1 = x[s1 * XPI + lane];
      float v2 = x[s2 * XPI + lane];
      float v3 = x[s3 * XPI + lane];
      a0 += w0.x*v0; a1 += w0.y*v0; a2 += w0.z*v0; a3 += w0.w*v0;
      a0 += w1.x*v1; a1 += w1.y*v1; a2 += w1.z*v1; a3 += w1.w*v1;
      a0 += w2.x*v2; a1 += w2.y*v2; a2 += w2.z*v2; a3 += w2.w*v2;
      a0 += w3.x*v3; a1 += w3.y*v3; a2 += w3.z*v3; a3 += w3.w*v3;
    }
    for (; k < end; ++k){
      int s = csr_src[k];
      float4 w = csr_w[k];
      float v = x[s * XPI + lane];
      a0 += w.x*v; a1 += w.y*v; a2 += w.z*v; a3 += w.w*v;
    }
    float* zrow = zs + team * ZS;
    zrow[0*XPI + lane] = a0;
    zrow[1*XPI + lane] = a1;
    zrow[2*XPI + lane] = a2;
    zrow[3*XPI + lane] = a3;
  }
  __syncthreads();

  // ---- phase 2 ----
  const int n = tid & (NPB - 1);
  const int j = tid / NPB;
  const int gnode = blockIdx.x * NPB + n;
  if (j < XPO && gnode < N){
    float v = 0.f;
    if (j < DOUT){
      float acc = b[j];
      const float* zrow = zs + n * ZS;
      const float* wrow = Wt + j * WTS;
      #pragma unroll 4
      for (int t = 0; t < R4; t += 4){
        float4 zv = *(const float4*)(zrow + t);
        float4 wv = *(const float4*)(wrow + t);
        acc += zv.x*wv.x + zv.y*wv.y + zv.z*wv.z + zv.w*wv.w;
      }
      v = elu_f(acc);
    }
    xout[gnode * XPO + j] = v;
  }
}

// ---------------- final MLP: 4 -> 8 -> 4 -> 1 (elu, elu, sigmoid) ----------------

__global__ __launch_bounds__(256) void mlp_kernel(
    const float* __restrict__ x,
    const float* __restrict__ lw1, const float* __restrict__ lb1,
    const float* __restrict__ lw2, const float* __restrict__ lb2,
    const float* __restrict__ lw3, const float* __restrict__ lb3,
    float* __restrict__ out, int N){
  int n = blockIdx.x*blockDim.x + threadIdx.x;
  if (n >= N) return;
  float4 xv = ((const float4*)x)[n];
  float x0[4] = {xv.x, xv.y, xv.z, xv.w};
  float h1[8];
  #pragma unroll
  for (int j=0;j<8;j++){
    float a = lb1[j];
    #pragma unroll
    for (int i=0;i<4;i++) a += x0[i]*lw1[i*8+j];
    h1[j] = elu_f(a);
  }
  float h2[4];
  #pragma unroll
  for (int j=0;j<4;j++){
    float a = lb2[j];
    #pragma unroll
    for (int i=0;i<8;i++) a += h1[i]*lw2[i*4+j];
    h2[j] = elu_f(a);
  }
  float a = lb3[0];
  #pragma unroll
  for (int i=0;i<4;i++) a += h2[i]*lw3[i];
  out[n] = 1.0f / (1.0f + expf(-a));
}

// ---------------- launch ----------------

extern "C" void kernel_launch(void* const* d_in, const int* in_sizes, int n_in,
                              void* d_out, int out_size, void* d_ws, size_t ws_size,
                              hipStream_t stream){
  const float* one_hot  = DF(d_in[0]);
  const float* features = DF(d_in[1]);
  const int*   src      = DI(d_in[3]);
  const int*   dst      = DI(d_in[4]);
  const float* ew       = DF(d_in[5]);
  const float* W1 = DF(d_in[6]);  const float* b1 = DF(d_in[7]);
  const float* W2 = DF(d_in[8]);  const float* b2 = DF(d_in[9]);
  const float* W3 = DF(d_in[10]); const float* b3 = DF(d_in[11]);
  const float* W4 = DF(d_in[12]); const float* b4 = DF(d_in[13]);
  const float* W5 = DF(d_in[14]); const float* b5 = DF(d_in[15]);
  const float* lw1 = DF(d_in[16]); const float* lb1 = DF(d_in[17]);
  const float* lw2 = DF(d_in[18]); const float* lb2 = DF(d_in[19]);
  const float* lw3 = DF(d_in[20]); const float* lb3 = DF(d_in[21]);
  float* out = (float*)d_out;

  const int N = in_sizes[0] / 20;   // 100000
  const int E = in_sizes[3];        // 3200000

  auto align = [](size_t x){ return (x + 255) & ~((size_t)255); };
  char* ws = (char*)d_ws;
  size_t off = 0;
  int*    rowptr  = (int*)(ws + off);    off = align(off + (size_t)(N+1)*4);
  int*    bsum    = (int*)(ws + off);    off = align(off + 4096);
  int*    csr_src = (int*)(ws + off);    off = align(off + (size_t)E*4);
  float4* csr_w   = (float4*)(ws + off); off = align(off + (size_t)E*16);
  // region D: csr_se (E*8) then xcat (N*64*4) -- csr_se dead before concat runs
  char*   regD    = ws + off;            off = align(off + (size_t)E*8);  // E*8 == N*64*4 here
  int2*   csr_se  = (int2*)regD;
  float*  xcat    = (float*)regD;
  // region E: rank (E*4) then xA (N*32*4) -- rank dead before L1 writes xA
  char*   regE    = ws + off;            off = align(off + (size_t)E*4);  // E*4 == N*32*4 here
  int*    rank    = (int*)regE;
  float*  xA      = (float*)regE;
  float*  xB      = (float*)(ws + off);  off = align(off + (size_t)N*16*4);
  float*  xC      = (float*)(ws + off);  off = align(off + (size_t)N*16*4);
  (void)ws_size;

  const int TB = 256;
  const int nbE = (E + TB - 1) / TB;
  const int nbN = (N + TB - 1) / TB;
  const int total = N + 1;
  const int nb1 = (total + 255) / 256;

  hipMemsetAsync(rowptr, 0, (size_t)(N+1)*4, stream);
  hist_kernel<<<nbE, TB, 0, stream>>>(dst, rowptr, rank, E);
  scan1_kernel<<<nb1, 256, 0, stream>>>(rowptr, bsum, total);
  scan2_kernel<<<1, 1024, 0, stream>>>(bsum, nb1);
  scan3_kernel<<<nb1, 256, 0, stream>>>(rowptr, bsum, total);
  scatter_kernel<<<nbE, TB, 0, stream>>>(src, dst, rank, rowptr, csr_se, E);
  build_kernel<<<nbE, TB, 0, stream>>>(csr_se, ew, csr_src, csr_w, E);

  concat_kernel<<<(N*64 + TB - 1)/TB, TB, 0, stream>>>(one_hot, features, xcat, N);

  // L1: 64 -> 20, in 64 (exact), out padded to 32
  layer_kernel<64,20,64,32><<<(N+3)/4,  TB, 0, stream>>>(rowptr, csr_src, csr_w, xcat, W1, b1, xA, N);
  // L2: 20 -> 16, in 32 (12 zero pads), out 16
  layer_kernel<20,16,32,16><<<(N+7)/8,  TB, 0, stream>>>(rowptr, csr_src, csr_w, xA, W2, b2, xB, N);
  // L3: 16 -> 12, in 16 (exact), out 16 (4 zero pads)
  layer_kernel<16,12,16,16><<<(N+15)/16, TB, 0, stream>>>(rowptr, csr_src, csr_w, xB, W3, b3, xC, N);
  // L4: 12 -> 8, in 16 (4 zero pads), out 16 (8 zero pads)
  layer_kernel<12, 8,16,16><<<(N+15)/16, TB, 0, stream>>>(rowptr, csr_src, csr_w, xC, W4, b4, xA, N);
  // L5: 8 -> 4, in 16 (8 zero pads), out 4 compact
  layer_kernel< 8, 4,16, 4><<<(N+15)/16, TB, 0, stream>>>(rowptr, csr_src, csr_w, xA, W5, b5, xB, N);

  mlp_kernel<<<nbN, TB, 0, stream>>>(xB, lw1, lb1, lw2, lb2, lw3, lb3, out, N);
}